// Round 1
// baseline (1573.198 us; speedup 1.0000x reference)
//
#include <hip/hip_runtime.h>

#define N_VARS  50000
#define N_EDGES 400000
#define HID     128

// ---------------------------------------------------------------------------
// Kernel 1: zero the s-accumulator (aliased onto d_out) and deg (in d_ws).
// Harness poisons d_out/d_ws with 0xAA before every timed launch.
// ---------------------------------------------------------------------------
__global__ __launch_bounds__(256) void zero_kernel(float* __restrict__ out,
                                                   int* __restrict__ deg) {
    int i = blockIdx.x * 256 + threadIdx.x;
    const int n4 = (N_VARS * HID) / 4;  // 1.6M float4
    float4* o4 = (float4*)out;
    if (i < n4) o4[i] = float4{0.f, 0.f, 0.f, 0.f};
    if (i < N_VARS) deg[i] = 0;
}

// ---------------------------------------------------------------------------
// Kernel 2: scatter-sum of x rows over directed (symmetrized) edges.
//   s[dst] += x[src];  deg[dst] += 1
// 32 threads per directed edge; each thread float4-gathers 16B of x[src]
// and does 4 global f32 atomicAdds into s[dst]. Directed edge i:
//   i <  E: (src,dst) = (e0[i], e1[i])
//   i >= E: (src,dst) = (e1[i-E], e0[i-E])
// where e0 = e[0..E), e1 = e[E..2E) (edge_idx is [2,E] row-major).
// ---------------------------------------------------------------------------
__global__ __launch_bounds__(256) void scatter_kernel(
    const float* __restrict__ x, const int* __restrict__ e,
    float* __restrict__ s, int* __restrict__ deg) {
    int gid  = blockIdx.x * 256 + threadIdx.x;
    int edge = gid >> 5;          // directed edge id
    int quad = gid & 31;          // which float4 of the 128-wide row
    if (edge >= 2 * N_EDGES) return;

    int i = (edge < N_EDGES) ? edge : edge - N_EDGES;
    int a = e[i];
    int b = e[N_EDGES + i];
    int src = (edge < N_EDGES) ? a : b;
    int dst = (edge < N_EDGES) ? b : a;

    const float4 v = ((const float4*)(x + (size_t)src * HID))[quad];
    float* srow = s + (size_t)dst * HID + quad * 4;
    atomicAdd(srow + 0, v.x);
    atomicAdd(srow + 1, v.y);
    atomicAdd(srow + 2, v.z);
    atomicAdd(srow + 3, v.w);
    if (quad == 0) atomicAdd(deg + dst, 1);
}

// ---------------------------------------------------------------------------
// Kernel 3: per-var combine, in place on d_out:
//   out[v] = s[v] @ W1^T + deg[v] * (x[v] @ W2^T)
// W[h][k], k in [0,256): thread t holds W[h=t&127][khalf*128 .. +128) in
// 128 VGPRs (one-time load per block, reused for all vars). vec (=[s|deg*x])
// is broadcast from LDS (wave-uniform address per j -> conflict-free).
// Each block owns a disjoint grid-stride set of vars -> in-place is safe.
// ---------------------------------------------------------------------------
__global__ __launch_bounds__(256) void combine_kernel(
    const float* __restrict__ x, const float* __restrict__ W,
    const int* __restrict__ deg, float* __restrict__ out) {
    __shared__ float vec[256];
    __shared__ float part[256];

    const int t     = threadIdx.x;
    const int h     = t & 127;
    const int khalf = t >> 7;   // 0: W1/s half, 1: W2/deg*x half

    // Load my 128-float strip of W into registers.
    float wreg[128];
    const float4* wrow = (const float4*)(W + h * 256 + khalf * 128);
#pragma unroll
    for (int j = 0; j < 32; ++j) {
        float4 w4 = wrow[j];
        wreg[4 * j + 0] = w4.x;
        wreg[4 * j + 1] = w4.y;
        wreg[4 * j + 2] = w4.z;
        wreg[4 * j + 3] = w4.w;
    }

    for (int v = blockIdx.x; v < N_VARS; v += gridDim.x) {
        float dv = (float)deg[v];
        __syncthreads();  // guard vec/part reuse from previous iteration
        if (t < 128)
            vec[t] = out[(size_t)v * HID + t];                 // s[v]
        else
            vec[t] = dv * x[(size_t)v * HID + (t - 128)];      // deg*x[v]
        __syncthreads();

        float acc = 0.f;
#pragma unroll
        for (int j = 0; j < 128; ++j)
            acc += vec[khalf * 128 + j] * wreg[j];
        part[t] = acc;
        __syncthreads();

        if (t < 128)
            out[(size_t)v * HID + t] = part[t] + part[t + 128];
    }
}

extern "C" void kernel_launch(void* const* d_in, const int* in_sizes, int n_in,
                              void* d_out, int out_size, void* d_ws, size_t ws_size,
                              hipStream_t stream) {
    const float* x = (const float*)d_in[0];   // [50000, 128] f32
    const float* W = (const float*)d_in[1];   // [128, 256] f32
    const int*   e = (const int*)d_in[2];     // [2, 400000] i32
    float* out = (float*)d_out;               // [50000, 128] f32, doubles as s
    int*   deg = (int*)d_ws;                  // [50000] i32

    // 1) zero s (= d_out) and deg
    {
        int n4 = (N_VARS * HID) / 4;
        int blocks = (n4 + 255) / 256;  // also covers N_VARS for deg
        zero_kernel<<<blocks, 256, 0, stream>>>(out, deg);
    }
    // 2) scatter: 2E edges * 32 threads
    {
        int threads = 2 * N_EDGES * 32;
        scatter_kernel<<<threads / 256, 256, 0, stream>>>(x, e, out, deg);
    }
    // 3) combine
    combine_kernel<<<1024, 256, 0, stream>>>(x, W, deg, out);
}

// Round 2
// 340.319 us; speedup vs baseline: 4.6227x; 4.6227x over previous
//
#include <hip/hip_runtime.h>

#define N_VARS  50000
#define N_EDGES 400000
#define HID     128
#define NDIR    (2 * N_EDGES)          // 800000 directed edges
#define NBLK    ((N_VARS + 255) / 256) // 196 scan blocks

// ws layout (ints): deg[50000] | offs[50001] | cursor[50000] | srcs[800000] | bsum[196]
#define WS_DEG    0
#define WS_OFFS   (N_VARS)
#define WS_CURSOR (WS_OFFS + N_VARS + 1)
#define WS_SRCS   (WS_CURSOR + N_VARS)
#define WS_BSUM   (WS_SRCS + NDIR)

// ---------------------------------------------------------------------------
// directed edge d in [0, 2E):  d < E: (src,dst)=(e0[d],e1[d]); else (e1,e0)
// ---------------------------------------------------------------------------
__device__ __forceinline__ void edge_endpoints(const int* __restrict__ e, int d,
                                               int& src, int& dst) {
    int i = (d < N_EDGES) ? d : d - N_EDGES;
    int a = e[i];
    int b = e[N_EDGES + i];
    src = (d < N_EDGES) ? a : b;
    dst = (d < N_EDGES) ? b : a;
}

__global__ __launch_bounds__(256) void zero_deg_kernel(int* __restrict__ deg) {
    int i = blockIdx.x * 256 + threadIdx.x;
    if (i < N_VARS) deg[i] = 0;
}

__global__ __launch_bounds__(256) void hist_kernel(const int* __restrict__ e,
                                                   int* __restrict__ deg) {
    int d = blockIdx.x * 256 + threadIdx.x;
    if (d >= NDIR) return;
    int src, dst;
    edge_endpoints(e, d, src, dst);
    atomicAdd(deg + dst, 1);
}

// ---- 3-kernel exclusive scan of deg -> offs (and cursor copy) -------------
__global__ __launch_bounds__(256) void scan1_kernel(const int* __restrict__ deg,
                                                    int* __restrict__ bsum) {
    __shared__ int lsum[4];
    int t = threadIdx.x;
    int i = blockIdx.x * 256 + t;
    int v = (i < N_VARS) ? deg[i] : 0;
    int w = v;
#pragma unroll
    for (int off = 32; off > 0; off >>= 1) w += __shfl_down(w, off, 64);
    if ((t & 63) == 0) lsum[t >> 6] = w;
    __syncthreads();
    if (t == 0) bsum[blockIdx.x] = lsum[0] + lsum[1] + lsum[2] + lsum[3];
}

__global__ __launch_bounds__(256) void scan2_kernel(int* __restrict__ bsum,
                                                    int* __restrict__ offs) {
    __shared__ int a[256];
    int t = threadIdx.x;
    a[t] = (t < NBLK) ? bsum[t] : 0;
    __syncthreads();
#pragma unroll
    for (int off = 1; off < 256; off <<= 1) {
        int add = (t >= off) ? a[t - off] : 0;
        __syncthreads();
        a[t] += add;
        __syncthreads();
    }
    // exclusive block offsets
    if (t < NBLK) bsum[t] = (t > 0) ? a[t - 1] : 0;
    if (t == 0) offs[N_VARS] = NDIR;  // total is a compile-time constant
}

__global__ __launch_bounds__(256) void scan3_kernel(const int* __restrict__ deg,
                                                    const int* __restrict__ bsum,
                                                    int* __restrict__ offs,
                                                    int* __restrict__ cursor) {
    __shared__ int a[256];
    int t = threadIdx.x;
    int i = blockIdx.x * 256 + t;
    int v = (i < N_VARS) ? deg[i] : 0;
    a[t] = v;
    __syncthreads();
#pragma unroll
    for (int off = 1; off < 256; off <<= 1) {
        int add = (t >= off) ? a[t - off] : 0;
        __syncthreads();
        a[t] += add;
        __syncthreads();
    }
    if (i < N_VARS) {
        int ex = bsum[blockIdx.x] + a[t] - v;  // exclusive prefix
        offs[i] = ex;
        cursor[i] = ex;
    }
}

// ---- bucket fill: srcs grouped by dst -------------------------------------
__global__ __launch_bounds__(256) void fill_kernel(const int* __restrict__ e,
                                                   int* __restrict__ cursor,
                                                   int* __restrict__ srcs) {
    int d = blockIdx.x * 256 + threadIdx.x;
    if (d >= NDIR) return;
    int src, dst;
    edge_endpoints(e, d, src, dst);
    int pos = atomicAdd(cursor + dst, 1);
    srcs[pos] = src;
}

// ---- gather-sum: s[v] = sum over incident srcs of x[src]; no atomics ------
// 32 lanes per var (float4 each), 8 vars per 256-thread block.
__global__ __launch_bounds__(256) void gather_kernel(const float* __restrict__ x,
                                                     const int* __restrict__ offs,
                                                     const int* __restrict__ srcs,
                                                     float* __restrict__ out) {
    int t = threadIdx.x;
    int v = blockIdx.x * 8 + (t >> 5);
    int lane = t & 31;
    if (v >= N_VARS) return;
    int o = offs[v];
    int n = offs[v + 1] - o;
    const float4* x4 = (const float4*)x;
    float4 acc = {0.f, 0.f, 0.f, 0.f};
    int j = 0;
    for (; j + 2 <= n; j += 2) {  // 2-deep ILP to hide gather latency
        int s0 = srcs[o + j];
        int s1 = srcs[o + j + 1];
        float4 a = x4[(size_t)s0 * 32 + lane];
        float4 b = x4[(size_t)s1 * 32 + lane];
        acc.x += a.x + b.x; acc.y += a.y + b.y;
        acc.z += a.z + b.z; acc.w += a.w + b.w;
    }
    if (j < n) {
        int s0 = srcs[o + j];
        float4 a = x4[(size_t)s0 * 32 + lane];
        acc.x += a.x; acc.y += a.y; acc.z += a.z; acc.w += a.w;
    }
    ((float4*)out)[(size_t)v * 32 + lane] = acc;
}

// ---------------------------------------------------------------------------
// combine (unchanged from R1): out[v] = s[v]@W1^T + deg[v]*(x[v]@W2^T)
// ---------------------------------------------------------------------------
__global__ __launch_bounds__(256) void combine_kernel(
    const float* __restrict__ x, const float* __restrict__ W,
    const int* __restrict__ deg, float* __restrict__ out) {
    __shared__ float vec[256];
    __shared__ float part[256];

    const int t     = threadIdx.x;
    const int h     = t & 127;
    const int khalf = t >> 7;

    float wreg[128];
    const float4* wrow = (const float4*)(W + h * 256 + khalf * 128);
#pragma unroll
    for (int j = 0; j < 32; ++j) {
        float4 w4 = wrow[j];
        wreg[4 * j + 0] = w4.x;
        wreg[4 * j + 1] = w4.y;
        wreg[4 * j + 2] = w4.z;
        wreg[4 * j + 3] = w4.w;
    }

    for (int v = blockIdx.x; v < N_VARS; v += gridDim.x) {
        float dv = (float)deg[v];
        __syncthreads();
        if (t < 128)
            vec[t] = out[(size_t)v * HID + t];
        else
            vec[t] = dv * x[(size_t)v * HID + (t - 128)];
        __syncthreads();

        float acc = 0.f;
#pragma unroll
        for (int j = 0; j < 128; ++j)
            acc += vec[khalf * 128 + j] * wreg[j];
        part[t] = acc;
        __syncthreads();

        if (t < 128)
            out[(size_t)v * HID + t] = part[t] + part[t + 128];
    }
}

extern "C" void kernel_launch(void* const* d_in, const int* in_sizes, int n_in,
                              void* d_out, int out_size, void* d_ws, size_t ws_size,
                              hipStream_t stream) {
    const float* x = (const float*)d_in[0];
    const float* W = (const float*)d_in[1];
    const int*   e = (const int*)d_in[2];
    float* out = (float*)d_out;

    int* wsi    = (int*)d_ws;
    int* deg    = wsi + WS_DEG;
    int* offs   = wsi + WS_OFFS;
    int* cursor = wsi + WS_CURSOR;
    int* srcs   = wsi + WS_SRCS;
    int* bsum   = wsi + WS_BSUM;

    zero_deg_kernel<<<NBLK, 256, 0, stream>>>(deg);
    hist_kernel<<<(NDIR + 255) / 256, 256, 0, stream>>>(e, deg);
    scan1_kernel<<<NBLK, 256, 0, stream>>>(deg, bsum);
    scan2_kernel<<<1, 256, 0, stream>>>(bsum, offs);
    scan3_kernel<<<NBLK, 256, 0, stream>>>(deg, bsum, offs, cursor);
    fill_kernel<<<(NDIR + 255) / 256, 256, 0, stream>>>(e, cursor, srcs);
    gather_kernel<<<(N_VARS + 7) / 8, 256, 0, stream>>>(x, offs, srcs, out);
    combine_kernel<<<1024, 256, 0, stream>>>(x, W, deg, out);
}

// Round 3
// 266.487 us; speedup vs baseline: 5.9035x; 1.2771x over previous
//
#include <hip/hip_runtime.h>

#define N_VARS  50000
#define N_EDGES 400000
#define HID     128
#define NDIR    (2 * N_EDGES)          // 800000 directed edges
#define NBLK    ((N_VARS + 255) / 256) // 196 scan blocks
#define MTILES  ((N_VARS + 15) / 16)   // 3125 m-tiles of 16 vars

// ws layout: y1b (bf16, [50000][128]) first (16B-aligned), then int area:
//   deg[50000] | offs[50001] | cursor[50000] | srcs[800000] | bsum[256]
#define Y1B_SHORTS (N_VARS * HID)          // 6.4M shorts = 12.8 MB
#define WS_INT0    (Y1B_SHORTS / 2)        // int offset of int area
#define WS_DEG     0
#define WS_OFFS    (N_VARS)
#define WS_CURSOR  (WS_OFFS + N_VARS + 1)
#define WS_SRCS    (WS_CURSOR + N_VARS)
#define WS_BSUM    (WS_SRCS + NDIR)

typedef __attribute__((ext_vector_type(8))) short bf16x8;
typedef __attribute__((ext_vector_type(4))) float f32x4;

__device__ __forceinline__ short f2bf(float f) {
    unsigned u = __builtin_bit_cast(unsigned, f);
    unsigned r = u + 0x7fffu + ((u >> 16) & 1u);  // round-to-nearest-even
    return (short)(r >> 16);
}

// directed edge d in [0, 2E):  d < E: (src,dst)=(e0[d],e1[d]); else swapped
__device__ __forceinline__ void edge_endpoints(const int* __restrict__ e, int d,
                                               int& src, int& dst) {
    int i = (d < N_EDGES) ? d : d - N_EDGES;
    int a = e[i];
    int b = e[N_EDGES + i];
    src = (d < N_EDGES) ? a : b;
    dst = (d < N_EDGES) ? b : a;
}

__global__ __launch_bounds__(256) void zero_deg_kernel(int* __restrict__ deg) {
    int i = blockIdx.x * 256 + threadIdx.x;
    if (i < N_VARS) deg[i] = 0;
}

__global__ __launch_bounds__(256) void hist_kernel(const int* __restrict__ e,
                                                   int* __restrict__ deg) {
    int d = blockIdx.x * 256 + threadIdx.x;
    if (d >= NDIR) return;
    int src, dst;
    edge_endpoints(e, d, src, dst);
    atomicAdd(deg + dst, 1);
}

// ---- 3-kernel exclusive scan of deg -> offs (and cursor copy) -------------
__global__ __launch_bounds__(256) void scan1_kernel(const int* __restrict__ deg,
                                                    int* __restrict__ bsum) {
    __shared__ int lsum[4];
    int t = threadIdx.x;
    int i = blockIdx.x * 256 + t;
    int v = (i < N_VARS) ? deg[i] : 0;
    int w = v;
#pragma unroll
    for (int off = 32; off > 0; off >>= 1) w += __shfl_down(w, off, 64);
    if ((t & 63) == 0) lsum[t >> 6] = w;
    __syncthreads();
    if (t == 0) bsum[blockIdx.x] = lsum[0] + lsum[1] + lsum[2] + lsum[3];
}

__global__ __launch_bounds__(256) void scan2_kernel(int* __restrict__ bsum,
                                                    int* __restrict__ offs) {
    __shared__ int a[256];
    int t = threadIdx.x;
    a[t] = (t < NBLK) ? bsum[t] : 0;
    __syncthreads();
#pragma unroll
    for (int off = 1; off < 256; off <<= 1) {
        int add = (t >= off) ? a[t - off] : 0;
        __syncthreads();
        a[t] += add;
        __syncthreads();
    }
    if (t < NBLK) bsum[t] = (t > 0) ? a[t - 1] : 0;
    if (t == 0) offs[N_VARS] = NDIR;
}

__global__ __launch_bounds__(256) void scan3_kernel(const int* __restrict__ deg,
                                                    const int* __restrict__ bsum,
                                                    int* __restrict__ offs,
                                                    int* __restrict__ cursor) {
    __shared__ int a[256];
    int t = threadIdx.x;
    int i = blockIdx.x * 256 + t;
    int v = (i < N_VARS) ? deg[i] : 0;
    a[t] = v;
    __syncthreads();
#pragma unroll
    for (int off = 1; off < 256; off <<= 1) {
        int add = (t >= off) ? a[t - off] : 0;
        __syncthreads();
        a[t] += add;
        __syncthreads();
    }
    if (i < N_VARS) {
        int ex = bsum[blockIdx.x] + a[t] - v;
        offs[i] = ex;
        cursor[i] = ex;
    }
}

__global__ __launch_bounds__(256) void fill_kernel(const int* __restrict__ e,
                                                   int* __restrict__ cursor,
                                                   int* __restrict__ srcs) {
    int d = blockIdx.x * 256 + threadIdx.x;
    if (d >= NDIR) return;
    int src, dst;
    edge_endpoints(e, d, src, dst);
    int pos = atomicAdd(cursor + dst, 1);
    srcs[pos] = src;
}

// ---------------------------------------------------------------------------
// GEMM: y[v][n] = sum_k x[v][k] * B[k][n],  B[k][n] = (n<128) ? W[n][k]
//                                                            : W[n-128][128+k]
//   n < 128  -> y1[v][n]         stored bf16 in ws
//   n >= 128 -> deg[v]*y2[v][n'] stored fp32 in d_out  (covers ALL of d_out)
// One wave per 16-var m-tile; 16 n-tiles x 4 k-chunks of mfma_f32_16x16x32_bf16.
// A/B converted fp32->bf16 on the fly (x and W stay fp32 in global).
// ---------------------------------------------------------------------------
__global__ __launch_bounds__(256) void gemm_kernel(const float* __restrict__ x,
                                                   const float* __restrict__ W,
                                                   const int* __restrict__ deg,
                                                   short* __restrict__ y1b,
                                                   float* __restrict__ out) {
    const int t    = threadIdx.x;
    const int lane = t & 63;
    const int wv   = t >> 6;
    const int mt   = blockIdx.x * 4 + wv;
    if (mt >= MTILES) return;
    const int m0   = mt * 16;
    const int ml   = lane & 15;          // m within tile (A) / n within tile (B,C)
    const int quad = lane >> 4;          // 0..3

    // A fragments: 4 k-chunks, lane holds x[m0+ml][kc*32+quad*8 .. +7] as bf16
    bf16x8 afrag[4];
#pragma unroll
    for (int kc = 0; kc < 4; ++kc) {
        const float4* ap = (const float4*)(x + (size_t)(m0 + ml) * HID + kc * 32 + quad * 8);
        float4 a0 = ap[0], a1 = ap[1];
        afrag[kc][0] = f2bf(a0.x); afrag[kc][1] = f2bf(a0.y);
        afrag[kc][2] = f2bf(a0.z); afrag[kc][3] = f2bf(a0.w);
        afrag[kc][4] = f2bf(a1.x); afrag[kc][5] = f2bf(a1.y);
        afrag[kc][6] = f2bf(a1.z); afrag[kc][7] = f2bf(a1.w);
    }

    // deg for my 4 C-rows (rows m0+quad*4+r)
    float dg[4];
#pragma unroll
    for (int r = 0; r < 4; ++r) dg[r] = (float)deg[m0 + quad * 4 + r];

#pragma unroll
    for (int nt = 0; nt < 16; ++nt) {
        const int n = nt * 16 + ml;
        // B fragment source row in W (contiguous 8 floats along k)
        const float* wp = (n < HID) ? (W + (size_t)n * 256)
                                    : (W + (size_t)(n - HID) * 256 + HID);
        f32x4 acc = {0.f, 0.f, 0.f, 0.f};
#pragma unroll
        for (int kc = 0; kc < 4; ++kc) {
            const float4* bp = (const float4*)(wp + kc * 32 + quad * 8);
            float4 b0 = bp[0], b1 = bp[1];
            bf16x8 bfrag;
            bfrag[0] = f2bf(b0.x); bfrag[1] = f2bf(b0.y);
            bfrag[2] = f2bf(b0.z); bfrag[3] = f2bf(b0.w);
            bfrag[4] = f2bf(b1.x); bfrag[5] = f2bf(b1.y);
            bfrag[6] = f2bf(b1.z); bfrag[7] = f2bf(b1.w);
            acc = __builtin_amdgcn_mfma_f32_16x16x32_bf16(afrag[kc], bfrag, acc, 0, 0, 0);
        }
        // C layout: col = lane&15 (= n), row = quad*4 + r
#pragma unroll
        for (int r = 0; r < 4; ++r) {
            const int row = m0 + quad * 4 + r;
            if (n < HID)
                y1b[(size_t)row * HID + n] = f2bf(acc[r]);
            else
                out[(size_t)row * HID + (n - HID)] = dg[r] * acc[r];
        }
    }
}

// ---------------------------------------------------------------------------
// gather: out[v] += sum over incident srcs of y1b[src] (bf16 rows, 256 B).
// 16 lanes per var (uint4 = 8 bf16 each), 16 vars per 256-thread block.
// ---------------------------------------------------------------------------
__global__ __launch_bounds__(256) void gather_kernel(const short* __restrict__ y1b,
                                                     const int* __restrict__ offs,
                                                     const int* __restrict__ srcs,
                                                     float* __restrict__ out) {
    const int t    = threadIdx.x;
    const int v    = blockIdx.x * 16 + (t >> 4);
    const int lane = t & 15;
    if (v >= N_VARS) return;
    const int o = offs[v];
    const int n = offs[v + 1] - o;

    const uint4* base = (const uint4*)y1b;  // row stride = 16 uint4
    float acc[8];
#pragma unroll
    for (int i = 0; i < 8; ++i) acc[i] = 0.f;

    auto accum = [&](uint4 a) {
        unsigned u[4] = {a.x, a.y, a.z, a.w};
#pragma unroll
        for (int w = 0; w < 4; ++w) {
            acc[2 * w + 0] += __builtin_bit_cast(float, u[w] << 16);
            acc[2 * w + 1] += __builtin_bit_cast(float, u[w] & 0xffff0000u);
        }
    };

    int j = 0;
    for (; j + 4 <= n; j += 4) {  // 4-deep ILP to hide L3 latency
        int s0 = srcs[o + j + 0], s1 = srcs[o + j + 1];
        int s2 = srcs[o + j + 2], s3 = srcs[o + j + 3];
        uint4 a0 = base[(size_t)s0 * 16 + lane];
        uint4 a1 = base[(size_t)s1 * 16 + lane];
        uint4 a2 = base[(size_t)s2 * 16 + lane];
        uint4 a3 = base[(size_t)s3 * 16 + lane];
        accum(a0); accum(a1); accum(a2); accum(a3);
    }
    for (; j < n; ++j) {
        int s0 = srcs[o + j];
        accum(base[(size_t)s0 * 16 + lane]);
    }

    float4* op = (float4*)(out + (size_t)v * HID + lane * 8);
    float4 o0 = op[0], o1 = op[1];
    o0.x += acc[0]; o0.y += acc[1]; o0.z += acc[2]; o0.w += acc[3];
    o1.x += acc[4]; o1.y += acc[5]; o1.z += acc[6]; o1.w += acc[7];
    op[0] = o0; op[1] = o1;
}

extern "C" void kernel_launch(void* const* d_in, const int* in_sizes, int n_in,
                              void* d_out, int out_size, void* d_ws, size_t ws_size,
                              hipStream_t stream) {
    const float* x = (const float*)d_in[0];
    const float* W = (const float*)d_in[1];
    const int*   e = (const int*)d_in[2];
    float* out = (float*)d_out;

    short* y1b  = (short*)d_ws;
    int*   wsi  = (int*)d_ws + WS_INT0;
    int* deg    = wsi + WS_DEG;
    int* offs   = wsi + WS_OFFS;
    int* cursor = wsi + WS_CURSOR;
    int* srcs   = wsi + WS_SRCS;
    int* bsum   = wsi + WS_BSUM;

    zero_deg_kernel<<<NBLK, 256, 0, stream>>>(deg);
    hist_kernel<<<(NDIR + 255) / 256, 256, 0, stream>>>(e, deg);
    scan1_kernel<<<NBLK, 256, 0, stream>>>(deg, bsum);
    scan2_kernel<<<1, 256, 0, stream>>>(bsum, offs);
    scan3_kernel<<<NBLK, 256, 0, stream>>>(deg, bsum, offs, cursor);
    fill_kernel<<<(NDIR + 255) / 256, 256, 0, stream>>>(e, cursor, srcs);
    gemm_kernel<<<(MTILES + 3) / 4, 256, 0, stream>>>(x, W, deg, y1b, out);
    gather_kernel<<<(N_VARS + 15) / 16, 256, 0, stream>>>(y1b, offs, srcs, out);
}

// Round 4
// 218.953 us; speedup vs baseline: 7.1851x; 1.2171x over previous
//
#include <hip/hip_runtime.h>

#define N_VARS  50000
#define N_EDGES 400000
#define HID     128
#define NDIR    (2 * N_EDGES)          // 800000 directed edges
#define NBLK    ((N_VARS + 255) / 256) // 196 scan blocks
#define MTILES  (N_VARS / 16)          // 3125 m-tiles (exact)

// ws layout (short-indexed for the bf16 region):
//   y1b [50000*128] | xb [50000*128] | wb [64*64*8] | int area
#define Y1B_OFF    0
#define XB_OFF     (N_VARS * HID)                  // 6,400,000 shorts
#define WB_OFF     (2 * N_VARS * HID)              // 12,800,000 shorts
#define WB_SHORTS  (64 * 64 * 8)                   // 32,768 shorts
#define WS_INT0    ((WB_OFF + WB_SHORTS) / 2)      // int offset of int area
// int area: deg[50000] | offs[50001] | cursor[50000] | srcs[800000] | bsum[256]
#define WS_DEG     0
#define WS_OFFS    (N_VARS)
#define WS_CURSOR  (WS_OFFS + N_VARS + 1)
#define WS_SRCS    (WS_CURSOR + N_VARS)
#define WS_BSUM    (WS_SRCS + NDIR)

typedef __attribute__((ext_vector_type(8))) short bf16x8;
typedef __attribute__((ext_vector_type(4))) float f32x4;

__device__ __forceinline__ short f2bf(float f) {
    unsigned u = __builtin_bit_cast(unsigned, f);
    unsigned r = u + 0x7fffu + ((u >> 16) & 1u);  // round-to-nearest-even
    return (short)(r >> 16);
}

__device__ __forceinline__ bf16x8 cvt8(float4 a0, float4 a1) {
    bf16x8 r;
    r[0] = f2bf(a0.x); r[1] = f2bf(a0.y); r[2] = f2bf(a0.z); r[3] = f2bf(a0.w);
    r[4] = f2bf(a1.x); r[5] = f2bf(a1.y); r[6] = f2bf(a1.z); r[7] = f2bf(a1.w);
    return r;
}

// directed edge d in [0, 2E):  d < E: (src,dst)=(e0[d],e1[d]); else swapped
__device__ __forceinline__ void edge_endpoints(const int* __restrict__ e, int d,
                                               int& src, int& dst) {
    int i = (d < N_EDGES) ? d : d - N_EDGES;
    int a = e[i];
    int b = e[N_EDGES + i];
    src = (d < N_EDGES) ? a : b;
    dst = (d < N_EDGES) ? b : a;
}

// ---------------------------------------------------------------------------
// prep (fused): xb = bf16(x); wb = fragment-ordered bf16 W; deg = 0.
// Fragment (nt in [0,16), kc in [0,4)), lane: ml=lane&15, quad=lane>>4,
//   n = nt*16+ml,  k_j = kc*32 + quad*8 + j,
//   source row: n<128 ? W[n][k] : W[n-128][128+k]   (W is [128][256] fp32)
// wb index (shorts): (nt*4+kc)*512 + lane*8 + j
// ---------------------------------------------------------------------------
__global__ __launch_bounds__(256) void prep_kernel(const float* __restrict__ x,
                                                   const float* __restrict__ W,
                                                   short* __restrict__ xb,
                                                   short* __restrict__ wb,
                                                   int* __restrict__ deg) {
    int gid = blockIdx.x * 256 + threadIdx.x;
    if (gid < N_VARS * HID / 8) {
        const float4* xp = (const float4*)x + (size_t)gid * 2;
        *(bf16x8*)(xb + (size_t)gid * 8) = cvt8(xp[0], xp[1]);
    }
    if (gid < N_VARS) deg[gid] = 0;
    if (gid < 4096) {
        int f = gid >> 6, lane = gid & 63;
        int nt = f >> 2, kc = f & 3;
        int ml = lane & 15, quad = lane >> 4;
        int n = nt * 16 + ml;
        const float* wp = (n < HID) ? (W + (size_t)n * 256)
                                    : (W + (size_t)(n - HID) * 256 + HID);
        wp += kc * 32 + quad * 8;
        const float4* w4 = (const float4*)wp;
        *(bf16x8*)(wb + (size_t)f * 512 + lane * 8) = cvt8(w4[0], w4[1]);
    }
}

__global__ __launch_bounds__(256) void hist_kernel(const int* __restrict__ e,
                                                   int* __restrict__ deg) {
    int d = blockIdx.x * 256 + threadIdx.x;
    if (d >= NDIR) return;
    int src, dst;
    edge_endpoints(e, d, src, dst);
    atomicAdd(deg + dst, 1);
}

// ---- 3-kernel exclusive scan of deg -> offs (and cursor copy) -------------
__global__ __launch_bounds__(256) void scan1_kernel(const int* __restrict__ deg,
                                                    int* __restrict__ bsum) {
    __shared__ int lsum[4];
    int t = threadIdx.x;
    int i = blockIdx.x * 256 + t;
    int v = (i < N_VARS) ? deg[i] : 0;
    int w = v;
#pragma unroll
    for (int off = 32; off > 0; off >>= 1) w += __shfl_down(w, off, 64);
    if ((t & 63) == 0) lsum[t >> 6] = w;
    __syncthreads();
    if (t == 0) bsum[blockIdx.x] = lsum[0] + lsum[1] + lsum[2] + lsum[3];
}

__global__ __launch_bounds__(256) void scan2_kernel(int* __restrict__ bsum,
                                                    int* __restrict__ offs) {
    __shared__ int a[256];
    int t = threadIdx.x;
    a[t] = (t < NBLK) ? bsum[t] : 0;
    __syncthreads();
#pragma unroll
    for (int off = 1; off < 256; off <<= 1) {
        int add = (t >= off) ? a[t - off] : 0;
        __syncthreads();
        a[t] += add;
        __syncthreads();
    }
    if (t < NBLK) bsum[t] = (t > 0) ? a[t - 1] : 0;
    if (t == 0) offs[N_VARS] = NDIR;
}

__global__ __launch_bounds__(256) void scan3_kernel(const int* __restrict__ deg,
                                                    const int* __restrict__ bsum,
                                                    int* __restrict__ offs,
                                                    int* __restrict__ cursor) {
    __shared__ int a[256];
    int t = threadIdx.x;
    int i = blockIdx.x * 256 + t;
    int v = (i < N_VARS) ? deg[i] : 0;
    a[t] = v;
    __syncthreads();
#pragma unroll
    for (int off = 1; off < 256; off <<= 1) {
        int add = (t >= off) ? a[t - off] : 0;
        __syncthreads();
        a[t] += add;
        __syncthreads();
    }
    if (i < N_VARS) {
        int ex = bsum[blockIdx.x] + a[t] - v;
        offs[i] = ex;
        cursor[i] = ex;
    }
}

__global__ __launch_bounds__(256) void fill_kernel(const int* __restrict__ e,
                                                   int* __restrict__ cursor,
                                                   int* __restrict__ srcs) {
    int d = blockIdx.x * 256 + threadIdx.x;
    if (d >= NDIR) return;
    int src, dst;
    edge_endpoints(e, d, src, dst);
    int pos = atomicAdd(cursor + dst, 1);
    srcs[pos] = src;
}

// ---------------------------------------------------------------------------
// GEMM: y[v][n] = sum_k xb[v][k] * B[k][n]  (all bf16 in, fp32 acc)
//   n < 128  -> y1b[v][n] (bf16, ws)
//   n >= 128 -> out[v][n-128] = deg[v] * y2 (fp32, covers ALL of d_out)
// Block = 4 waves; wave wv owns n in [wv*64, wv*64+64) (4 n-tiles) with its
// 16 B-fragments held in 64 VGPRs (loaded once from wb). 2 m-tiles per block.
// wv<2 -> pure y1b writes; wv>=2 -> pure out writes (wave-uniform, no diverg).
// ---------------------------------------------------------------------------
__global__ __launch_bounds__(256) void gemm_kernel(const short* __restrict__ xb,
                                                   const short* __restrict__ wb,
                                                   const int* __restrict__ deg,
                                                   short* __restrict__ y1b,
                                                   float* __restrict__ out) {
    const int t    = threadIdx.x;
    const int lane = t & 63;
    const int wv   = t >> 6;
    const int ml   = lane & 15;
    const int quad = lane >> 4;

    // B fragments for my 4 n-tiles: loaded once, reused for all m-tiles.
    bf16x8 bfrag[4][4];
#pragma unroll
    for (int i = 0; i < 4; ++i)
#pragma unroll
        for (int kc = 0; kc < 4; ++kc)
            bfrag[i][kc] = *(const bf16x8*)(wb + (size_t)((wv * 4 + i) * 4 + kc) * 512 + lane * 8);

#pragma unroll
    for (int mi = 0; mi < 2; ++mi) {
        const int mt = blockIdx.x * 2 + mi;
        if (mt >= MTILES) break;
        const int m0 = mt * 16;

        bf16x8 afrag[4];
#pragma unroll
        for (int kc = 0; kc < 4; ++kc)
            afrag[kc] = *(const bf16x8*)(xb + (size_t)(m0 + ml) * HID + kc * 32 + quad * 8);

        f32x4 acc[4];
#pragma unroll
        for (int i = 0; i < 4; ++i) acc[i] = f32x4{0.f, 0.f, 0.f, 0.f};
#pragma unroll
        for (int kc = 0; kc < 4; ++kc)
#pragma unroll
            for (int i = 0; i < 4; ++i)
                acc[i] = __builtin_amdgcn_mfma_f32_16x16x32_bf16(afrag[kc], bfrag[i][kc], acc[i], 0, 0, 0);

        // C layout: col = lane&15 (within n-tile), row = quad*4 + r
        if (wv < 2) {
#pragma unroll
            for (int i = 0; i < 4; ++i) {
                const int n = wv * 64 + i * 16 + ml;
#pragma unroll
                for (int r = 0; r < 4; ++r) {
                    const int row = m0 + quad * 4 + r;
                    y1b[(size_t)row * HID + n] = f2bf(acc[i][r]);
                }
            }
        } else {
            float dg[4];
#pragma unroll
            for (int r = 0; r < 4; ++r) dg[r] = (float)deg[m0 + quad * 4 + r];
#pragma unroll
            for (int i = 0; i < 4; ++i) {
                const int col = (wv - 2) * 64 + i * 16 + ml;
#pragma unroll
                for (int r = 0; r < 4; ++r) {
                    const int row = m0 + quad * 4 + r;
                    out[(size_t)row * HID + col] = dg[r] * acc[i][r];
                }
            }
        }
    }
}

// ---------------------------------------------------------------------------
// gather: out[v] += sum over incident srcs of y1b[src] (bf16 rows, 256 B).
// 16 lanes per var (uint4 = 8 bf16 each), 16 vars per 256-thread block.
// ---------------------------------------------------------------------------
__global__ __launch_bounds__(256) void gather_kernel(const short* __restrict__ y1b,
                                                     const int* __restrict__ offs,
                                                     const int* __restrict__ srcs,
                                                     float* __restrict__ out) {
    const int t    = threadIdx.x;
    const int v    = blockIdx.x * 16 + (t >> 4);
    const int lane = t & 15;
    if (v >= N_VARS) return;
    const int o = offs[v];
    const int n = offs[v + 1] - o;

    const uint4* base = (const uint4*)y1b;  // row stride = 16 uint4
    float acc[8];
#pragma unroll
    for (int i = 0; i < 8; ++i) acc[i] = 0.f;

    auto accum = [&](uint4 a) {
        unsigned u[4] = {a.x, a.y, a.z, a.w};
#pragma unroll
        for (int w = 0; w < 4; ++w) {
            acc[2 * w + 0] += __builtin_bit_cast(float, u[w] << 16);
            acc[2 * w + 1] += __builtin_bit_cast(float, u[w] & 0xffff0000u);
        }
    };

    int j = 0;
    for (; j + 4 <= n; j += 4) {  // 4-deep ILP to hide cache latency
        int s0 = srcs[o + j + 0], s1 = srcs[o + j + 1];
        int s2 = srcs[o + j + 2], s3 = srcs[o + j + 3];
        uint4 a0 = base[(size_t)s0 * 16 + lane];
        uint4 a1 = base[(size_t)s1 * 16 + lane];
        uint4 a2 = base[(size_t)s2 * 16 + lane];
        uint4 a3 = base[(size_t)s3 * 16 + lane];
        accum(a0); accum(a1); accum(a2); accum(a3);
    }
    for (; j < n; ++j) {
        int s0 = srcs[o + j];
        accum(base[(size_t)s0 * 16 + lane]);
    }

    float4* op = (float4*)(out + (size_t)v * HID + lane * 8);
    float4 o0 = op[0], o1 = op[1];
    o0.x += acc[0]; o0.y += acc[1]; o0.z += acc[2]; o0.w += acc[3];
    o1.x += acc[4]; o1.y += acc[5]; o1.z += acc[6]; o1.w += acc[7];
    op[0] = o0; op[1] = o1;
}

extern "C" void kernel_launch(void* const* d_in, const int* in_sizes, int n_in,
                              void* d_out, int out_size, void* d_ws, size_t ws_size,
                              hipStream_t stream) {
    const float* x = (const float*)d_in[0];
    const float* W = (const float*)d_in[1];
    const int*   e = (const int*)d_in[2];
    float* out = (float*)d_out;

    short* wss  = (short*)d_ws;
    short* y1b  = wss + Y1B_OFF;
    short* xb   = wss + XB_OFF;
    short* wb   = wss + WB_OFF;
    int*   wsi  = (int*)d_ws + WS_INT0;
    int* deg    = wsi + WS_DEG;
    int* offs   = wsi + WS_OFFS;
    int* cursor = wsi + WS_CURSOR;
    int* srcs   = wsi + WS_SRCS;
    int* bsum   = wsi + WS_BSUM;

    prep_kernel<<<(N_VARS * HID / 8 + 255) / 256, 256, 0, stream>>>(x, W, xb, wb, deg);
    hist_kernel<<<(NDIR + 255) / 256, 256, 0, stream>>>(e, deg);
    scan1_kernel<<<NBLK, 256, 0, stream>>>(deg, bsum);
    scan2_kernel<<<1, 256, 0, stream>>>(bsum, offs);
    scan3_kernel<<<NBLK, 256, 0, stream>>>(deg, bsum, offs, cursor);
    fill_kernel<<<(NDIR + 255) / 256, 256, 0, stream>>>(e, cursor, srcs);
    gemm_kernel<<<(MTILES + 1) / 2, 256, 0, stream>>>(xb, wb, deg, y1b, out);
    gather_kernel<<<(N_VARS + 15) / 16, 256, 0, stream>>>(y1b, offs, srcs, out);
}

// Round 5
// 183.081 us; speedup vs baseline: 8.5929x; 1.1959x over previous
//
#include <hip/hip_runtime.h>

#define N_VARS  50000
#define N_EDGES 400000
#define HID     128
#define NDIR    (2 * N_EDGES)          // 800000 directed edges
#define MTILES  (N_VARS / 16)          // 3125 m-tiles (exact)
#define CAP     64                     // bucket capacity per dst (mean deg = 16)
#define OVF_CAP 8192

// ws layout:
//   shorts: y1b [N_VARS*HID] | wb [64*64*8] | srcs (ushort) [N_VARS*CAP]
//   ints  : cursor [N_VARS] | ovf_cnt [1] | ovf [OVF_CAP]
#define Y1B_OFF  0
#define WB_OFF   (N_VARS * HID)                   // 6,400,000 shorts
#define WB_SH    (64 * 64 * 8)                    // 32,768 shorts
#define SRC_OFF  (WB_OFF + WB_SH)                 // shorts
#define INT0     ((SRC_OFF + N_VARS * CAP) / 2)   // int offset (even ✓)

typedef __attribute__((ext_vector_type(8))) short bf16x8;
typedef __attribute__((ext_vector_type(4))) float f32x4;

__device__ __forceinline__ short f2bf(float f) {
    unsigned u = __builtin_bit_cast(unsigned, f);
    unsigned r = u + 0x7fffu + ((u >> 16) & 1u);  // round-to-nearest-even
    return (short)(r >> 16);
}

__device__ __forceinline__ bf16x8 cvt8(float4 a0, float4 a1) {
    bf16x8 r;
    r[0] = f2bf(a0.x); r[1] = f2bf(a0.y); r[2] = f2bf(a0.z); r[3] = f2bf(a0.w);
    r[4] = f2bf(a1.x); r[5] = f2bf(a1.y); r[6] = f2bf(a1.z); r[7] = f2bf(a1.w);
    return r;
}

// ---------------------------------------------------------------------------
// prep: wb = fragment-ordered bf16 W; cursor = 0; ovf_cnt = 0.
// Fragment (nt,kc), lane: ml=lane&15, quad=lane>>4, n=nt*16+ml,
//   k_j = kc*32+quad*8+j; source: n<128 ? W[n][k] : W[n-128][128+k].
// wb index (shorts): (nt*4+kc)*512 + lane*8 + j
// ---------------------------------------------------------------------------
__global__ __launch_bounds__(256) void prep_kernel(const float* __restrict__ W,
                                                   short* __restrict__ wb,
                                                   int* __restrict__ cursor,
                                                   int* __restrict__ ovf_cnt) {
    int gid = blockIdx.x * 256 + threadIdx.x;
    if (gid < N_VARS) cursor[gid] = 0;
    if (gid == N_VARS) *ovf_cnt = 0;
    if (gid < 4096) {
        int f = gid >> 6, lane = gid & 63;
        int nt = f >> 2, kc = f & 3;
        int ml = lane & 15, quad = lane >> 4;
        int n = nt * 16 + ml;
        const float* wp = (n < HID) ? (W + (size_t)n * 256)
                                    : (W + (size_t)(n - HID) * 256 + HID);
        wp += kc * 32 + quad * 8;
        const float4* w4 = (const float4*)wp;
        *(bf16x8*)(wb + (size_t)f * 512 + lane * 8) = cvt8(w4[0], w4[1]);
    }
}

// ---------------------------------------------------------------------------
// GEMM: y[v][n] = sum_k bf16(x[v][k]) * B[k][n]
//   n < 128  -> y1b[v][n] (bf16, ws)      n >= 128 -> out[v][n-128] (fp32,
//   UNSCALED y2 — gather applies the deg scale). Covers all of d_out.
// Block = 4 waves; wave wv owns 4 n-tiles, B-frags resident in 64 VGPRs.
// 2 m-tiles per block; A converted fp32->bf16 inline (no xb pass).
// ---------------------------------------------------------------------------
__global__ __launch_bounds__(256) void gemm_kernel(const float* __restrict__ x,
                                                   const short* __restrict__ wb,
                                                   short* __restrict__ y1b,
                                                   float* __restrict__ out) {
    const int t    = threadIdx.x;
    const int lane = t & 63;
    const int wv   = t >> 6;
    const int ml   = lane & 15;
    const int quad = lane >> 4;

    bf16x8 bfrag[4][4];
#pragma unroll
    for (int i = 0; i < 4; ++i)
#pragma unroll
        for (int kc = 0; kc < 4; ++kc)
            bfrag[i][kc] = *(const bf16x8*)(wb + (size_t)((wv * 4 + i) * 4 + kc) * 512 + lane * 8);

#pragma unroll
    for (int mi = 0; mi < 2; ++mi) {
        const int mt = blockIdx.x * 2 + mi;
        if (mt >= MTILES) break;
        const int m0 = mt * 16;

        bf16x8 afrag[4];
#pragma unroll
        for (int kc = 0; kc < 4; ++kc) {
            const float4* ap = (const float4*)(x + (size_t)(m0 + ml) * HID + kc * 32 + quad * 8);
            afrag[kc] = cvt8(ap[0], ap[1]);
        }

        f32x4 acc[4];
#pragma unroll
        for (int i = 0; i < 4; ++i) acc[i] = f32x4{0.f, 0.f, 0.f, 0.f};
#pragma unroll
        for (int kc = 0; kc < 4; ++kc)
#pragma unroll
            for (int i = 0; i < 4; ++i)
                acc[i] = __builtin_amdgcn_mfma_f32_16x16x32_bf16(afrag[kc], bfrag[i][kc], acc[i], 0, 0, 0);

        // C layout: col = lane&15 (within n-tile), row = quad*4 + r
        if (wv < 2) {
#pragma unroll
            for (int i = 0; i < 4; ++i) {
                const int n = wv * 64 + i * 16 + ml;
#pragma unroll
                for (int r = 0; r < 4; ++r)
                    y1b[(size_t)(m0 + quad * 4 + r) * HID + n] = f2bf(acc[i][r]);
            }
        } else {
#pragma unroll
            for (int i = 0; i < 4; ++i) {
                const int col = (wv - 2) * 64 + i * 16 + ml;
#pragma unroll
                for (int r = 0; r < 4; ++r)
                    out[(size_t)(m0 + quad * 4 + r) * HID + col] = acc[i][r];
            }
        }
    }
}

// ---------------------------------------------------------------------------
// fill: bucket scatter. pos = cursor[dst]++; srcs[dst*CAP+pos] = src (ushort).
// cursor ends as the full degree (including overflow). Bucket rows are
// 128 B-aligned and fill from 0 -> a dst's ~16 entries live in ONE 64 B line.
// ---------------------------------------------------------------------------
__global__ __launch_bounds__(256) void fill_kernel(const int* __restrict__ e,
                                                   int* __restrict__ cursor,
                                                   unsigned short* __restrict__ srcs,
                                                   int* __restrict__ ovf_cnt,
                                                   int* __restrict__ ovf) {
    int d = blockIdx.x * 256 + threadIdx.x;   // grid exactly covers NDIR
    int i = (d < N_EDGES) ? d : d - N_EDGES;
    int a = e[i];
    int b = e[N_EDGES + i];
    int src = (d < N_EDGES) ? a : b;
    int dst = (d < N_EDGES) ? b : a;
    int pos = atomicAdd(cursor + dst, 1);
    if (pos < CAP) {
        srcs[(size_t)dst * CAP + pos] = (unsigned short)src;
    } else {
        int o = atomicAdd(ovf_cnt, 1);
        if (o < OVF_CAP) ovf[o] = (src << 16) | dst;
    }
}

// ---------------------------------------------------------------------------
// gather: out[v] = deg[v]*out_gemm[v] + sum_{src in bucket[v]} y1b[src]
// 16 lanes per var (uint4 = 8 bf16), 16 vars per block, 4-deep ILP.
// ---------------------------------------------------------------------------
__global__ __launch_bounds__(256) void gather_kernel(const short* __restrict__ y1b,
                                                     const int* __restrict__ cursor,
                                                     const unsigned short* __restrict__ srcs,
                                                     float* __restrict__ out) {
    const int t    = threadIdx.x;
    const int v    = blockIdx.x * 16 + (t >> 4);
    const int lane = t & 15;
    const int c = cursor[v];
    const int n = (c < CAP) ? c : CAP;
    const unsigned short* bucket = srcs + (size_t)v * CAP;

    const uint4* base = (const uint4*)y1b;  // row stride = 16 uint4
    float acc[8];
#pragma unroll
    for (int i = 0; i < 8; ++i) acc[i] = 0.f;

    auto accum = [&](uint4 a) {
        unsigned u[4] = {a.x, a.y, a.z, a.w};
#pragma unroll
        for (int w = 0; w < 4; ++w) {
            acc[2 * w + 0] += __builtin_bit_cast(float, u[w] << 16);
            acc[2 * w + 1] += __builtin_bit_cast(float, u[w] & 0xffff0000u);
        }
    };

    int j = 0;
    for (; j + 4 <= n; j += 4) {
        int s0 = bucket[j + 0], s1 = bucket[j + 1];
        int s2 = bucket[j + 2], s3 = bucket[j + 3];
        uint4 a0 = base[(size_t)s0 * 16 + lane];
        uint4 a1 = base[(size_t)s1 * 16 + lane];
        uint4 a2 = base[(size_t)s2 * 16 + lane];
        uint4 a3 = base[(size_t)s3 * 16 + lane];
        accum(a0); accum(a1); accum(a2); accum(a3);
    }
    for (; j < n; ++j) {
        int s0 = bucket[j];
        accum(base[(size_t)s0 * 16 + lane]);
    }

    const float dg = (float)c;
    float4* op = (float4*)(out + (size_t)v * HID + lane * 8);
    float4 o0 = op[0], o1 = op[1];
    o0.x = dg * o0.x + acc[0]; o0.y = dg * o0.y + acc[1];
    o0.z = dg * o0.z + acc[2]; o0.w = dg * o0.w + acc[3];
    o1.x = dg * o1.x + acc[4]; o1.y = dg * o1.y + acc[5];
    o1.z = dg * o1.z + acc[6]; o1.w = dg * o1.w + acc[7];
    op[0] = o0; op[1] = o1;
}

// ---------------------------------------------------------------------------
// overflow cleanup: exact f32 atomic adds for bucket-overflow edges.
// Normally zero entries (P(deg>64) ~ 1e-20) — pure insurance, ~1 µs.
// ---------------------------------------------------------------------------
__global__ __launch_bounds__(256) void ovf_kernel(const short* __restrict__ y1b,
                                                  const int* __restrict__ ovf_cnt,
                                                  const int* __restrict__ ovf,
                                                  float* __restrict__ out) {
    int n = *ovf_cnt;
    if (n > OVF_CAP) n = OVF_CAP;
    for (int idx = threadIdx.x; idx < n * HID; idx += 256) {
        int entry = idx >> 7, col = idx & 127;
        int packed = ovf[entry];
        int src = packed >> 16, dst = packed & 0xffff;
        unsigned u = (unsigned)(unsigned short)y1b[(size_t)src * HID + col] << 16;
        atomicAdd(out + (size_t)dst * HID + col, __builtin_bit_cast(float, u));
    }
}

extern "C" void kernel_launch(void* const* d_in, const int* in_sizes, int n_in,
                              void* d_out, int out_size, void* d_ws, size_t ws_size,
                              hipStream_t stream) {
    const float* x = (const float*)d_in[0];
    const float* W = (const float*)d_in[1];
    const int*   e = (const int*)d_in[2];
    float* out = (float*)d_out;

    short* wss = (short*)d_ws;
    short* y1b = wss + Y1B_OFF;
    short* wb  = wss + WB_OFF;
    unsigned short* srcs = (unsigned short*)(wss + SRC_OFF);
    int* wsi     = (int*)d_ws + INT0;
    int* cursor  = wsi;
    int* ovf_cnt = wsi + N_VARS;
    int* ovf     = wsi + N_VARS + 1;

    prep_kernel<<<(N_VARS + 256) / 256, 256, 0, stream>>>(W, wb, cursor, ovf_cnt);
    gemm_kernel<<<(MTILES + 1) / 2, 256, 0, stream>>>(x, wb, y1b, out);
    fill_kernel<<<NDIR / 256, 256, 0, stream>>>(e, cursor, srcs, ovf_cnt, ovf);
    gather_kernel<<<N_VARS / 16, 256, 0, stream>>>(y1b, cursor, srcs, out);
    ovf_kernel<<<1, 256, 0, stream>>>(y1b, ovf_cnt, ovf, out);
}

// Round 7
// 151.031 us; speedup vs baseline: 10.4164x; 1.2122x over previous
//
#include <hip/hip_runtime.h>

#define N_VARS   50000
#define N_EDGES  400000
#define NDIR     (2 * N_EDGES)
#define HID      128
#define MTILES   (N_VARS / 16)      // 3125
#define NBKT     196                // coarse buckets: dst >> 8
#define CCAP     4608               // coarse capacity (mean 4082, +8 sigma)
#define NDST_PAD (NBKT * 256)       // 50176
#define CAP      32                 // fine bucket capacity (mean deg 16)
#define OVF_CAP  4096
#define ABLOCKS  391                // ceil(400000 / 1024)

// ws layout
//   shorts: y1b [N_VARS*HID] | wb [64*64*8] | srcs (ushort) [NDST_PAD*CAP]
//   ints  : gcount[NBKT] | ovf_cnt[1] | ovf[OVF_CAP] | cursor[NDST_PAD]
//           | extra[NDST_PAD] | coarse[NBKT*CCAP]
#define Y1B_OFF 0
#define WB_OFF  (N_VARS * HID)                    // 6,400,000
#define WB_SH   (64 * 64 * 8)                     // 32,768
#define SRC_OFF (WB_OFF + WB_SH)
#define INT0    ((SRC_OFF + NDST_PAD * CAP) / 2)  // even

#define I_GCOUNT 0
#define I_OVFCNT (I_GCOUNT + NBKT)
#define I_OVF    (I_OVFCNT + 1)
#define I_CURSOR (I_OVF + OVF_CAP)
#define I_EXTRA  (I_CURSOR + NDST_PAD)
#define I_COARSE (I_EXTRA + NDST_PAD)

typedef __attribute__((ext_vector_type(8))) short bf16x8;
typedef __attribute__((ext_vector_type(4))) float f32x4;

__device__ __forceinline__ short f2bf(float f) {
    unsigned u = __builtin_bit_cast(unsigned, f);
    unsigned r = u + 0x7fffu + ((u >> 16) & 1u);  // round-to-nearest-even
    return (short)(r >> 16);
}

__device__ __forceinline__ bf16x8 cvt8(float4 a0, float4 a1) {
    bf16x8 r;
    r[0] = f2bf(a0.x); r[1] = f2bf(a0.y); r[2] = f2bf(a0.z); r[3] = f2bf(a0.w);
    r[4] = f2bf(a1.x); r[5] = f2bf(a1.y); r[6] = f2bf(a1.z); r[7] = f2bf(a1.w);
    return r;
}

// ---------------------------------------------------------------------------
// prep: wb = fragment-ordered bf16 W; zero gcount / ovf_cnt / extra.
// ---------------------------------------------------------------------------
__global__ __launch_bounds__(256) void prep_kernel(const float* __restrict__ W,
                                                   short* __restrict__ wb,
                                                   int* __restrict__ gcount,
                                                   int* __restrict__ ovf_cnt,
                                                   int* __restrict__ extra) {
    int gid = blockIdx.x * 256 + threadIdx.x;
    if (gid < NBKT) gcount[gid] = 0;
    if (gid == NBKT) *ovf_cnt = 0;
    if (gid < NDST_PAD) extra[gid] = 0;
    if (gid < 4096) {
        int f = gid >> 6, lane = gid & 63;
        int nt = f >> 2, kc = f & 3;
        int ml = lane & 15, quad = lane >> 4;
        int n = nt * 16 + ml;
        const float* wp = (n < HID) ? (W + (size_t)n * 256)
                                    : (W + (size_t)(n - HID) * 256 + HID);
        wp += kc * 32 + quad * 8;
        const float4* w4 = (const float4*)wp;
        *(bf16x8*)(wb + (size_t)f * 512 + lane * 8) = cvt8(w4[0], w4[1]);
    }
}

// ---------------------------------------------------------------------------
// GEMM: y[v][n] = sum_k bf16(x[v][k]) * B[k][n]
//   n < 128 -> y1b (bf16 ws);  n >= 128 -> out (fp32, UNSCALED y2).
// ---------------------------------------------------------------------------
__global__ __launch_bounds__(256) void gemm_kernel(const float* __restrict__ x,
                                                   const short* __restrict__ wb,
                                                   short* __restrict__ y1b,
                                                   float* __restrict__ out) {
    const int t    = threadIdx.x;
    const int lane = t & 63;
    const int wv   = t >> 6;
    const int ml   = lane & 15;
    const int quad = lane >> 4;

    bf16x8 bfrag[4][4];
#pragma unroll
    for (int i = 0; i < 4; ++i)
#pragma unroll
        for (int kc = 0; kc < 4; ++kc)
            bfrag[i][kc] = *(const bf16x8*)(wb + (size_t)((wv * 4 + i) * 4 + kc) * 512 + lane * 8);

#pragma unroll
    for (int mi = 0; mi < 2; ++mi) {
        const int mt = blockIdx.x * 2 + mi;
        if (mt >= MTILES) break;
        const int m0 = mt * 16;

        bf16x8 afrag[4];
#pragma unroll
        for (int kc = 0; kc < 4; ++kc) {
            const float4* ap = (const float4*)(x + (size_t)(m0 + ml) * HID + kc * 32 + quad * 8);
            afrag[kc] = cvt8(ap[0], ap[1]);
        }

        f32x4 acc[4];
#pragma unroll
        for (int i = 0; i < 4; ++i) acc[i] = f32x4{0.f, 0.f, 0.f, 0.f};
#pragma unroll
        for (int kc = 0; kc < 4; ++kc)
#pragma unroll
            for (int i = 0; i < 4; ++i)
                acc[i] = __builtin_amdgcn_mfma_f32_16x16x32_bf16(afrag[kc], bfrag[i][kc], acc[i], 0, 0, 0);

        if (wv < 2) {
#pragma unroll
            for (int i = 0; i < 4; ++i) {
                const int n = wv * 64 + i * 16 + ml;
#pragma unroll
                for (int r = 0; r < 4; ++r)
                    y1b[(size_t)(m0 + quad * 4 + r) * HID + n] = f2bf(acc[i][r]);
            }
        } else {
#pragma unroll
            for (int i = 0; i < 4; ++i) {
                const int col = (wv - 2) * 64 + i * 16 + ml;
#pragma unroll
                for (int r = 0; r < 4; ++r)
                    out[(size_t)(m0 + quad * 4 + r) * HID + col] = acc[i][r];
            }
        }
    }
}

// ---------------------------------------------------------------------------
// binA: coarse scatter. Each block bins 1024 undirected edges (2048 directed)
// into NBKT coarse buckets via LDS counts, reserves per-bucket runs with one
// global atomic per bucket, then stores packed (src<<8 | dst&255) in dense
// runs (~10 entries each) -> line-friendly writes.
// ---------------------------------------------------------------------------
__global__ __launch_bounds__(256) void binA_kernel(const int* __restrict__ e,
                                                   int* __restrict__ gcount,
                                                   int* __restrict__ coarse,
                                                   int* __restrict__ extra,
                                                   int* __restrict__ ovf_cnt,
                                                   unsigned* __restrict__ ovf) {
    __shared__ int cnt[NBKT];
    __shared__ int base[NBKT];
    const int t = threadIdx.x;
    for (int i = t; i < NBKT; i += 256) cnt[i] = 0;
    __syncthreads();

    int e0[4], e1[4], nb = 0;
    const int b0 = (blockIdx.x * 256 + t) * 4;
    if (blockIdx.x < ABLOCKS - 1) {
        int4 A = *(const int4*)(e + b0);
        int4 B = *(const int4*)(e + N_EDGES + b0);
        e0[0] = A.x; e0[1] = A.y; e0[2] = A.z; e0[3] = A.w;
        e1[0] = B.x; e1[1] = B.y; e1[2] = B.z; e1[3] = B.w;
        nb = 4;
    } else {
        for (int j = 0; j < 4; ++j)
            if (b0 + j < N_EDGES) { e0[nb] = e[b0 + j]; e1[nb] = e[N_EDGES + b0 + j]; ++nb; }
    }

    int bkt[8], lpos[8], pk[8];
#pragma unroll 4
    for (int j = 0; j < nb; ++j) {
        int a = e0[j], b = e1[j];
        bkt[2 * j]     = b >> 8;                     // direction a->b (dst=b)
        pk[2 * j]      = (a << 8) | (b & 255);
        lpos[2 * j]    = atomicAdd(&cnt[b >> 8], 1);
        bkt[2 * j + 1] = a >> 8;                     // direction b->a (dst=a)
        pk[2 * j + 1]  = (b << 8) | (a & 255);
        lpos[2 * j + 1] = atomicAdd(&cnt[a >> 8], 1);
    }
    __syncthreads();
    for (int i = t; i < NBKT; i += 256)
        base[i] = (cnt[i] > 0) ? atomicAdd(&gcount[i], cnt[i]) : 0;
    __syncthreads();

    for (int j = 0; j < 2 * nb; ++j) {
        int p = base[bkt[j]] + lpos[j];
        if (p < CCAP) {
            coarse[bkt[j] * CCAP + p] = pk[j];
        } else {  // statistically ~impossible; handled exactly anyway
            unsigned src = (unsigned)(pk[j] >> 8);
            unsigned dst = (unsigned)((bkt[j] << 8) | (pk[j] & 255));
            atomicAdd(&extra[dst], 1);
            int o = atomicAdd(ovf_cnt, 1);
            if (o < OVF_CAP) ovf[o] = (src << 16) | dst;  // unsigned pack
        }
    }
}

// ---------------------------------------------------------------------------
// binB: one block per coarse bucket (256 dsts). Builds fine per-dst buckets
// in LDS (LDS atomics), then streams them out as dense 16 KB copies and
// writes cursor (= true per-dst arrival count).
// ---------------------------------------------------------------------------
__global__ __launch_bounds__(256) void binB_kernel(const int* __restrict__ gcount,
                                                   const int* __restrict__ coarse,
                                                   unsigned short* __restrict__ srcs,
                                                   int* __restrict__ cursor,
                                                   int* __restrict__ ovf_cnt,
                                                   unsigned* __restrict__ ovf) {
    __shared__ int fcnt[256];
    __shared__ unsigned short fine[256 * CAP];  // 16 KB
    const int t = threadIdx.x, b = blockIdx.x;
    fcnt[t] = 0;
    __syncthreads();

    int n = gcount[b];
    if (n > CCAP) n = CCAP;
    const int* cb = coarse + b * CCAP;

    int i = t;
    int p = (i < n) ? cb[i] : 0;
    while (i < n) {
        int pn = (i + 256 < n) ? cb[i + 256] : 0;   // prefetch next
        int dl = p & 255;
        unsigned src = (unsigned)(p >> 8);          // p >= 0: logical-equivalent
        int pos = atomicAdd(&fcnt[dl], 1);
        if (pos < CAP) {
            fine[dl * CAP + pos] = (unsigned short)src;
        } else {
            int o = atomicAdd(ovf_cnt, 1);
            if (o < OVF_CAP) ovf[o] = (src << 16) | (unsigned)(b * 256 + dl);
        }
        p = pn;
        i += 256;
    }
    __syncthreads();

    const uint4* fs = (const uint4*)fine;
    uint4* gs = (uint4*)(srcs + (size_t)b * 256 * CAP);
#pragma unroll
    for (int k = 0; k < 4; ++k) gs[k * 256 + t] = fs[k * 256 + t];
    cursor[b * 256 + t] = fcnt[t];
}

// ---------------------------------------------------------------------------
// gather: out[v] = deg[v]*y2[v] + sum_{src in fine bucket[v]} y1b[src]
// deg = cursor + extra (extra only nonzero under coarse overflow).
// 16 lanes per var (uint4 = 8 bf16), 16 vars per block, 4-deep ILP.
// ---------------------------------------------------------------------------
__global__ __launch_bounds__(256) void gather_kernel(const short* __restrict__ y1b,
                                                     const int* __restrict__ cursor,
                                                     const int* __restrict__ extra,
                                                     const unsigned short* __restrict__ srcs,
                                                     float* __restrict__ out) {
    const int t    = threadIdx.x;
    const int v    = blockIdx.x * 16 + (t >> 4);
    const int lane = t & 15;
    const int c = cursor[v];
    const int n = (c < CAP) ? c : CAP;
    const unsigned short* bucket = srcs + (size_t)v * CAP;

    const uint4* base = (const uint4*)y1b;
    float acc[8];
#pragma unroll
    for (int i = 0; i < 8; ++i) acc[i] = 0.f;

    auto accum = [&](uint4 a) {
        unsigned u[4] = {a.x, a.y, a.z, a.w};
#pragma unroll
        for (int w = 0; w < 4; ++w) {
            acc[2 * w + 0] += __builtin_bit_cast(float, u[w] << 16);
            acc[2 * w + 1] += __builtin_bit_cast(float, u[w] & 0xffff0000u);
        }
    };

    int j = 0;
    for (; j + 4 <= n; j += 4) {
        int s0 = bucket[j + 0], s1 = bucket[j + 1];
        int s2 = bucket[j + 2], s3 = bucket[j + 3];
        uint4 a0 = base[(size_t)s0 * 16 + lane];
        uint4 a1 = base[(size_t)s1 * 16 + lane];
        uint4 a2 = base[(size_t)s2 * 16 + lane];
        uint4 a3 = base[(size_t)s3 * 16 + lane];
        accum(a0); accum(a1); accum(a2); accum(a3);
    }
    for (; j < n; ++j) accum(base[(size_t)bucket[j] * 16 + lane]);

    const float dg = (float)(c + extra[v]);
    float4* op = (float4*)(out + (size_t)v * HID + lane * 8);
    float4 o0 = op[0], o1 = op[1];
    o0.x = dg * o0.x + acc[0]; o0.y = dg * o0.y + acc[1];
    o0.z = dg * o0.z + acc[2]; o0.w = dg * o0.w + acc[3];
    o1.x = dg * o1.x + acc[4]; o1.y = dg * o1.y + acc[5];
    o1.z = dg * o1.z + acc[6]; o1.w = dg * o1.w + acc[7];
    op[0] = o0; op[1] = o1;
}

// ---------------------------------------------------------------------------
// overflow cleanup (fine + coarse): exact f32 atomic adds of y1b[src] rows.
// UNSIGNED unpack (src>=32768 must not sign-extend — this was the r6 bug).
// ---------------------------------------------------------------------------
__global__ __launch_bounds__(256) void ovf_kernel(const short* __restrict__ y1b,
                                                  const int* __restrict__ ovf_cnt,
                                                  const unsigned* __restrict__ ovf,
                                                  float* __restrict__ out) {
    int n = *ovf_cnt;
    if (n > OVF_CAP) n = OVF_CAP;
    for (int idx = blockIdx.x * 256 + threadIdx.x; idx < n * HID; idx += 8 * 256) {
        int entry = idx >> 7, col = idx & 127;
        unsigned packed = ovf[entry];
        int src = (int)(packed >> 16);        // logical shift: src in [0, 65536)
        int dst = (int)(packed & 0xffffu);
        unsigned u = (unsigned)(unsigned short)y1b[(size_t)src * HID + col] << 16;
        atomicAdd(out + (size_t)dst * HID + col, __builtin_bit_cast(float, u));
    }
}

extern "C" void kernel_launch(void* const* d_in, const int* in_sizes, int n_in,
                              void* d_out, int out_size, void* d_ws, size_t ws_size,
                              hipStream_t stream) {
    const float* x = (const float*)d_in[0];
    const float* W = (const float*)d_in[1];
    const int*   e = (const int*)d_in[2];
    float* out = (float*)d_out;

    short* wss = (short*)d_ws;
    short* y1b = wss + Y1B_OFF;
    short* wb  = wss + WB_OFF;
    unsigned short* srcs = (unsigned short*)(wss + SRC_OFF);
    int* wsi     = (int*)d_ws + INT0;
    int* gcount  = wsi + I_GCOUNT;
    int* ovf_cnt = wsi + I_OVFCNT;
    unsigned* ovf = (unsigned*)(wsi + I_OVF);
    int* cursor  = wsi + I_CURSOR;
    int* extra   = wsi + I_EXTRA;
    int* coarse  = wsi + I_COARSE;

    prep_kernel<<<(NDST_PAD + 255) / 256, 256, 0, stream>>>(W, wb, gcount, ovf_cnt, extra);
    gemm_kernel<<<(MTILES + 1) / 2, 256, 0, stream>>>(x, wb, y1b, out);
    binA_kernel<<<ABLOCKS, 256, 0, stream>>>(e, gcount, coarse, extra, ovf_cnt, ovf);
    binB_kernel<<<NBKT, 256, 0, stream>>>(gcount, coarse, srcs, cursor, ovf_cnt, ovf);
    gather_kernel<<<N_VARS / 16, 256, 0, stream>>>(y1b, cursor, extra, srcs, out);
    ovf_kernel<<<8, 256, 0, stream>>>(y1b, ovf_cnt, ovf, out);
}

// Round 9
// 134.200 us; speedup vs baseline: 11.7228x; 1.1254x over previous
//
#include <hip/hip_runtime.h>

#define N_VARS   50000
#define N_EDGES  400000
#define NDIR     (2 * N_EDGES)
#define HID      128
#define MTILES   (N_VARS / 16)        // 3125
#define GEMM_BLOCKS ((MTILES + 1) / 2) // 1563
#define NBKT     196                  // coarse buckets: dst >> 8
#define CCAP     4608                 // coarse capacity (mean 4082, +8 sigma)
#define NDST_PAD (NBKT * 256)         // 50176
#define CAP      32                   // fine bucket capacity (mean deg 16)
#define OVF_CAP  4096
#define ABLOCKS  391                  // ceil(400000 / 1024)

// ws layout (byte offsets):
//   y1f8 (fp8 e4m3) [N_VARS*128] | wb (bf16) [64*64*8] | srcs (ushort)
//   [NDST_PAD*CAP] | ints: gcount[NBKT] | ovf_cnt[1] | ovf[OVF_CAP]
//   | cursor[NDST_PAD] | extra[NDST_PAD] | coarse[NBKT*CCAP]
#define Y1_BYTES  (N_VARS * HID)                 // 6,400,000
#define WB_BYTE0  Y1_BYTES
#define WB_BYTES  (64 * 64 * 8 * 2)              // 65,536
#define SRC_BYTE0 (WB_BYTE0 + WB_BYTES)
#define SRC_BYTES (NDST_PAD * CAP * 2)
#define INT_BYTE0 (SRC_BYTE0 + SRC_BYTES)        // % 4 == 0

#define I_GCOUNT 0
#define I_OVFCNT (I_GCOUNT + NBKT)
#define I_OVF    (I_OVFCNT + 1)
#define I_CURSOR (I_OVF + OVF_CAP)
#define I_EXTRA  (I_CURSOR + NDST_PAD)
#define I_COARSE (I_EXTRA + NDST_PAD)

typedef __attribute__((ext_vector_type(8))) short bf16x8;
typedef __attribute__((ext_vector_type(4))) float f32x4;
typedef __attribute__((ext_vector_type(2))) float f32x2;

__device__ __forceinline__ short f2bf(float f) {
    unsigned u = __builtin_bit_cast(unsigned, f);
    unsigned r = u + 0x7fffu + ((u >> 16) & 1u);  // RNE
    return (short)(r >> 16);
}

__device__ __forceinline__ bf16x8 cvt8(float4 a0, float4 a1) {
    bf16x8 r;
    r[0] = f2bf(a0.x); r[1] = f2bf(a0.y); r[2] = f2bf(a0.z); r[3] = f2bf(a0.w);
    r[4] = f2bf(a1.x); r[5] = f2bf(a1.y); r[6] = f2bf(a1.z); r[7] = f2bf(a1.w);
    return r;
}

// ---------------------------------------------------------------------------
// prep: wb = fragment-ordered bf16 W; zero gcount / ovf_cnt / extra.
// wb fragment (nt,kc), lane: ml=lane&15, quad=lane>>4, n=nt*16+ml,
//   k_j = kc*32+quad*8+j; source: n<128 ? W[n][k] : W[n-128][128+k].
// ---------------------------------------------------------------------------
__global__ __launch_bounds__(256) void prep_kernel(const float* __restrict__ W,
                                                   short* __restrict__ wb,
                                                   int* __restrict__ gcount,
                                                   int* __restrict__ ovf_cnt,
                                                   int* __restrict__ extra) {
    int gid = blockIdx.x * 256 + threadIdx.x;
    if (gid < NBKT) gcount[gid] = 0;
    if (gid == NBKT) *ovf_cnt = 0;
    if (gid < NDST_PAD) extra[gid] = 0;
    if (gid < 4096) {
        int f = gid >> 6, lane = gid & 63;
        int nt = f >> 2, kc = f & 3;
        int ml = lane & 15, quad = lane >> 4;
        int n = nt * 16 + ml;
        const float* wp = (n < HID) ? (W + (size_t)n * 256)
                                    : (W + (size_t)(n - HID) * 256 + HID);
        wp += kc * 32 + quad * 8;
        const float4* w4 = (const float4*)wp;
        *(bf16x8*)(wb + (size_t)f * 512 + lane * 8) = cvt8(w4[0], w4[1]);
    }
}

// ---------------------------------------------------------------------------
// Fused gemm + binA. blockIdx < GEMM_BLOCKS: GEMM; else: coarse edge binning.
//
// GEMM (operand-swapped): acc = mfma(wbfrag, xfrag, acc) computes the
// TRANSPOSED tile D[n][v]: lane ml = v, rows quad*4+r = 4 CONSECUTIVE n.
//   wv<2 : y1 -> fp8 e4m3, one packed dword store per n-tile per lane
//   wv>=2: y2 -> out fp32 UNSCALED, one float4 store per n-tile per lane
// ---------------------------------------------------------------------------
__global__ __launch_bounds__(256) void gemm_binA_kernel(
    const float* __restrict__ x, const short* __restrict__ wb,
    unsigned char* __restrict__ y1f8, float* __restrict__ out,
    const int* __restrict__ e, int* __restrict__ gcount,
    int* __restrict__ coarse, int* __restrict__ extra,
    int* __restrict__ ovf_cnt, unsigned* __restrict__ ovf) {
    __shared__ int cnt[NBKT];
    __shared__ int base[NBKT];
    const int t = threadIdx.x;

    if (blockIdx.x < GEMM_BLOCKS) {
        // ---------------- GEMM ----------------
        const int lane = t & 63;
        const int wv   = t >> 6;
        const int ml   = lane & 15;
        const int quad = lane >> 4;

        bf16x8 bfrag[4][4];
#pragma unroll
        for (int i = 0; i < 4; ++i)
#pragma unroll
            for (int kc = 0; kc < 4; ++kc)
                bfrag[i][kc] = *(const bf16x8*)(wb + (size_t)((wv * 4 + i) * 4 + kc) * 512 + lane * 8);

#pragma unroll
        for (int mi = 0; mi < 2; ++mi) {
            const int mt = blockIdx.x * 2 + mi;
            if (mt >= MTILES) break;
            const int m0 = mt * 16;
            const int v  = m0 + ml;

            bf16x8 afrag[4];
#pragma unroll
            for (int kc = 0; kc < 4; ++kc) {
                const float4* ap = (const float4*)(x + (size_t)v * HID + kc * 32 + quad * 8);
                afrag[kc] = cvt8(ap[0], ap[1]);
            }

            f32x4 acc[4];
#pragma unroll
            for (int i = 0; i < 4; ++i) acc[i] = f32x4{0.f, 0.f, 0.f, 0.f};
#pragma unroll
            for (int kc = 0; kc < 4; ++kc)
#pragma unroll
                for (int i = 0; i < 4; ++i)  // SWAPPED operands -> D[n][v]
                    acc[i] = __builtin_amdgcn_mfma_f32_16x16x32_bf16(bfrag[i][kc], afrag[kc], acc[i], 0, 0, 0);

            if (wv < 2) {
#pragma unroll
                for (int i = 0; i < 4; ++i) {
                    int w = __builtin_amdgcn_cvt_pk_fp8_f32(acc[i][0], acc[i][1], 0, false);
                    w     = __builtin_amdgcn_cvt_pk_fp8_f32(acc[i][2], acc[i][3], w, true);
                    *(int*)(y1f8 + (size_t)v * HID + wv * 64 + i * 16 + quad * 4) = w;
                }
            } else {
#pragma unroll
                for (int i = 0; i < 4; ++i) {
                    float4 o = {acc[i][0], acc[i][1], acc[i][2], acc[i][3]};
                    *(float4*)(out + (size_t)v * HID + (wv - 2) * 64 + i * 16 + quad * 4) = o;
                }
            }
        }
    } else {
        // ---------------- binA: coarse edge binning ----------------
        const int bA = blockIdx.x - GEMM_BLOCKS;
        for (int i = t; i < NBKT; i += 256) cnt[i] = 0;
        __syncthreads();

        int e0[4], e1[4], nb = 0;
        const int b0 = (bA * 256 + t) * 4;
        if (bA < ABLOCKS - 1) {
            int4 A = *(const int4*)(e + b0);
            int4 B = *(const int4*)(e + N_EDGES + b0);
            e0[0] = A.x; e0[1] = A.y; e0[2] = A.z; e0[3] = A.w;
            e1[0] = B.x; e1[1] = B.y; e1[2] = B.z; e1[3] = B.w;
            nb = 4;
        } else {
            for (int j = 0; j < 4; ++j)
                if (b0 + j < N_EDGES) { e0[nb] = e[b0 + j]; e1[nb] = e[N_EDGES + b0 + j]; ++nb; }
        }

        int bkt[8], lpos[8], pk[8];
#pragma unroll 4
        for (int j = 0; j < nb; ++j) {
            int a = e0[j], b = e1[j];
            bkt[2 * j]      = b >> 8;
            pk[2 * j]       = (a << 8) | (b & 255);
            lpos[2 * j]     = atomicAdd(&cnt[b >> 8], 1);
            bkt[2 * j + 1]  = a >> 8;
            pk[2 * j + 1]   = (b << 8) | (a & 255);
            lpos[2 * j + 1] = atomicAdd(&cnt[a >> 8], 1);
        }
        __syncthreads();
        for (int i = t; i < NBKT; i += 256)
            base[i] = (cnt[i] > 0) ? atomicAdd(&gcount[i], cnt[i]) : 0;
        __syncthreads();

        for (int j = 0; j < 2 * nb; ++j) {
            int p = base[bkt[j]] + lpos[j];
            if (p < CCAP) {
                coarse[bkt[j] * CCAP + p] = pk[j];
            } else {  // exact fallback, statistically never
                unsigned src = (unsigned)(pk[j] >> 8);
                unsigned dst = (unsigned)((bkt[j] << 8) | (pk[j] & 255));
                atomicAdd(&extra[dst], 1);
                int o = atomicAdd(ovf_cnt, 1);
                if (o < OVF_CAP) ovf[o] = (src << 16) | dst;
            }
        }
    }
}

// ---------------------------------------------------------------------------
// binB: one block per coarse bucket (256 dsts). Fine per-dst buckets in LDS,
// dense 16 KB stream-out, cursor = true arrival count.
// ---------------------------------------------------------------------------
__global__ __launch_bounds__(256) void binB_kernel(const int* __restrict__ gcount,
                                                   const int* __restrict__ coarse,
                                                   unsigned short* __restrict__ srcs,
                                                   int* __restrict__ cursor,
                                                   int* __restrict__ ovf_cnt,
                                                   unsigned* __restrict__ ovf) {
    __shared__ int fcnt[256];
    __shared__ unsigned short fine[256 * CAP];  // 16 KB
    const int t = threadIdx.x, b = blockIdx.x;
    fcnt[t] = 0;
    __syncthreads();

    int n = gcount[b];
    if (n > CCAP) n = CCAP;
    const int* cb = coarse + b * CCAP;

    int i = t;
    int p = (i < n) ? cb[i] : 0;
    while (i < n) {
        int pn = (i + 256 < n) ? cb[i + 256] : 0;
        int dl = p & 255;
        unsigned src = (unsigned)(p >> 8);
        int pos = atomicAdd(&fcnt[dl], 1);
        if (pos < CAP) {
            fine[dl * CAP + pos] = (unsigned short)src;
        } else {
            int o = atomicAdd(ovf_cnt, 1);
            if (o < OVF_CAP) ovf[o] = (src << 16) | (unsigned)(b * 256 + dl);
        }
        p = pn;
        i += 256;
    }
    __syncthreads();

    const uint4* fs = (const uint4*)fine;
    uint4* gs = (uint4*)(srcs + (size_t)b * 256 * CAP);
#pragma unroll
    for (int k = 0; k < 4; ++k) gs[k * 256 + t] = fs[k * 256 + t];
    cursor[b * 256 + t] = fcnt[t];
}

// ---------------------------------------------------------------------------
// gather: out[v] = deg[v]*y2[v] + sum_{src in bucket[v]} fp8dec(y1f8[src])
// 8 lanes per var (uint4 = 16 fp8 each), 32 vars per block, 4-deep ILP.
// fp8 decode via packed cvt_pk_f32_fp8 (word select is a literal constant).
// ---------------------------------------------------------------------------
__global__ __launch_bounds__(256) void gather_kernel(const unsigned char* __restrict__ y1f8,
                                                     const int* __restrict__ cursor,
                                                     const int* __restrict__ extra,
                                                     const unsigned short* __restrict__ srcs,
                                                     float* __restrict__ out) {
    const int t    = threadIdx.x;
    const int v    = blockIdx.x * 32 + (t >> 3);
    const int lane = t & 7;
    if (v >= N_VARS) return;
    const int c = cursor[v];
    const int n = (c < CAP) ? c : CAP;
    const unsigned short* bucket = srcs + (size_t)v * CAP;

    const uint4* base = (const uint4*)y1f8;  // row stride = 8 uint4 (128 B)
    float acc[16];
#pragma unroll
    for (int i = 0; i < 16; ++i) acc[i] = 0.f;

    auto accum = [&](uint4 a) {
        int u[4] = {(int)a.x, (int)a.y, (int)a.z, (int)a.w};
#pragma unroll
        for (int w = 0; w < 4; ++w) {
            f32x2 lo = __builtin_amdgcn_cvt_pk_f32_fp8(u[w], false);
            f32x2 hi = __builtin_amdgcn_cvt_pk_f32_fp8(u[w], true);
            acc[4 * w + 0] += lo[0];
            acc[4 * w + 1] += lo[1];
            acc[4 * w + 2] += hi[0];
            acc[4 * w + 3] += hi[1];
        }
    };

    int j = 0;
    for (; j + 4 <= n; j += 4) {
        int s0 = bucket[j + 0], s1 = bucket[j + 1];
        int s2 = bucket[j + 2], s3 = bucket[j + 3];
        uint4 a0 = base[(size_t)s0 * 8 + lane];
        uint4 a1 = base[(size_t)s1 * 8 + lane];
        uint4 a2 = base[(size_t)s2 * 8 + lane];
        uint4 a3 = base[(size_t)s3 * 8 + lane];
        accum(a0); accum(a1); accum(a2); accum(a3);
    }
    for (; j < n; ++j) accum(base[(size_t)bucket[j] * 8 + lane]);

    const float dg = (float)(c + extra[v]);
    float4* op = (float4*)(out + (size_t)v * HID + lane * 16);
#pragma unroll
    for (int q = 0; q < 4; ++q) {
        float4 o = op[q];
        o.x = dg * o.x + acc[4 * q + 0];
        o.y = dg * o.y + acc[4 * q + 1];
        o.z = dg * o.z + acc[4 * q + 2];
        o.w = dg * o.w + acc[4 * q + 3];
        op[q] = o;
    }
}

// ---------------------------------------------------------------------------
// overflow cleanup: exact f32 atomic adds of decoded y1f8[src] rows.
// ---------------------------------------------------------------------------
__global__ __launch_bounds__(256) void ovf_kernel(const unsigned char* __restrict__ y1f8,
                                                  const int* __restrict__ ovf_cnt,
                                                  const unsigned* __restrict__ ovf,
                                                  float* __restrict__ out) {
    int n = *ovf_cnt;
    if (n > OVF_CAP) n = OVF_CAP;
    for (int idx = blockIdx.x * 256 + threadIdx.x; idx < n * HID; idx += 8 * 256) {
        int entry = idx >> 7, col = idx & 127;
        unsigned packed = ovf[entry];
        int src = (int)(packed >> 16);
        int dst = (int)(packed & 0xffffu);
        float val = __builtin_amdgcn_cvt_f32_fp8((int)y1f8[(size_t)src * HID + col], 0);
        atomicAdd(out + (size_t)dst * HID + col, val);
    }
}

extern "C" void kernel_launch(void* const* d_in, const int* in_sizes, int n_in,
                              void* d_out, int out_size, void* d_ws, size_t ws_size,
                              hipStream_t stream) {
    const float* x = (const float*)d_in[0];
    const float* W = (const float*)d_in[1];
    const int*   e = (const int*)d_in[2];
    float* out = (float*)d_out;

    unsigned char* wsb = (unsigned char*)d_ws;
    unsigned char* y1f8 = wsb;
    short* wb = (short*)(wsb + WB_BYTE0);
    unsigned short* srcs = (unsigned short*)(wsb + SRC_BYTE0);
    int* wsi      = (int*)(wsb + INT_BYTE0);
    int* gcount   = wsi + I_GCOUNT;
    int* ovf_cnt  = wsi + I_OVFCNT;
    unsigned* ovf = (unsigned*)(wsi + I_OVF);
    int* cursor   = wsi + I_CURSOR;
    int* extra    = wsi + I_EXTRA;
    int* coarse   = wsi + I_COARSE;

    prep_kernel<<<NDST_PAD / 256, 256, 0, stream>>>(W, wb, gcount, ovf_cnt, extra);
    gemm_binA_kernel<<<GEMM_BLOCKS + ABLOCKS, 256, 0, stream>>>(
        x, wb, y1f8, out, e, gcount, coarse, extra, ovf_cnt, ovf);
    binB_kernel<<<NBKT, 256, 0, stream>>>(gcount, coarse, srcs, cursor, ovf_cnt, ovf);
    gather_kernel<<<(N_VARS + 31) / 32, 256, 0, stream>>>(y1f8, cursor, extra, srcs, out);
    ovf_kernel<<<8, 256, 0, stream>>>(y1f8, ovf_cnt, ovf, out);
}